// Round 15
// baseline (33.011 us; speedup 1.0000x reference)
//
#include <hip/hip_runtime.h>
#include <math.h>

#define Bdim 64
#define Tdim 512
#define Sdim 400
#define Hdim 768
#define Ldim 9
#define PSTRIDE 12  // padded proj row stride

#define TPW 32  // tokens per wave (slab never crosses a batch row: 512/32=16)

// ---------------------------------------------------------------------------
// DPP 64-lane sum (row_shr 1/2/4/8 + row_bcast 15/31), result in lane 63.
// ---------------------------------------------------------------------------
template <int CTRL>
__device__ __forceinline__ float dpp_add(float x) {
  int y = __builtin_amdgcn_update_dpp(0, __float_as_int(x), CTRL, 0xF, 0xF, false);
  return x + __int_as_float(y);
}
__device__ __forceinline__ float wave_sum63(float x) {
  x = dpp_add<0x111>(x);
  x = dpp_add<0x112>(x);
  x = dpp_add<0x114>(x);
  x = dpp_add<0x118>(x);
  x = dpp_add<0x142>(x);
  x = dpp_add<0x143>(x);
  return x;  // lane 63 = sum of all 64 lanes
}

// ---------------------------------------------------------------------------
// Kernel 1: wave-per-token projection, ALL 9 logits per wave (no redundancy:
// each enc byte load-issued exactly once, fully coalesced). W fragment =
// 108 floats/lane, register-resident under launch_bounds(256,2) (R5's
// failure was (256,3)'s 85-VGPR cap forcing silent rematerialization).
// Wave owns a 32-token slab; prefix mask => slab valid count via one ballot;
// exact-bound ping-pong prefetch (valid-only bytes, straight-line pipeline).
// Block 0 zeroes the loss accumulators (ws is not re-poisoned).
// ---------------------------------------------------------------------------
__global__ __launch_bounds__(256, 2) void proj_kernel(
    const float* __restrict__ enc, const float* __restrict__ W,
    const int* __restrict__ attn, float* __restrict__ proj,
    float* __restrict__ accum, unsigned* __restrict__ counter) {
  int tid = threadIdx.x;
  int lane = tid & 63;
  int wv = (blockIdx.x << 2) | (tid >> 6);  // 1024 waves
  int t0 = wv * TPW;

  if (blockIdx.x == 0) {
    if (tid < 2) accum[tid] = 0.0f;
    if (tid == 2) *counter = 0u;
  }

  // slab valid count: lanes 0..31 probe attn, first zero = count (prefix mask)
  int mb = attn[t0 + (lane & 31)];
  unsigned long long bal = __ballot(mb != 0);
  unsigned low = (unsigned)bal;
  unsigned inv = ~low;
  int vc = inv ? (__ffs(inv) - 1) : 32;
  if (vc == 0) return;

  // W fragment: h = 4*lane + 256*c + j (c<3, j<4), ALL 9 logits
  float wf[3][4][Ldim];
#pragma unroll
  for (int c = 0; c < 3; ++c)
#pragma unroll
    for (int j = 0; j < 4; ++j) {
      int h = 4 * lane + 256 * c + j;
#pragma unroll
      for (int l = 0; l < Ldim; ++l) wf[c][j][l] = W[(size_t)h * Ldim + l];
    }

  const float4* encf4 = (const float4*)enc;

  float4 A0, A1, A2, B0, B1, B2;
#define LDT(V0, V1, V2, K)                                                 \
  {                                                                        \
    const float4* r_ = encf4 + (size_t)(t0 + (K)) * (Hdim / 4);            \
    V0 = r_[lane]; V1 = r_[lane + 64]; V2 = r_[lane + 128];                \
  }
#define PRT(V0, V1, V2, K)                                                 \
  {                                                                        \
    float dd[Ldim];                                                        \
    _Pragma("unroll") for (int l = 0; l < Ldim; ++l) {                     \
      dd[l] = V0.x * wf[0][0][l] + V0.y * wf[0][1][l] +                    \
              V0.z * wf[0][2][l] + V0.w * wf[0][3][l] +                    \
              V1.x * wf[1][0][l] + V1.y * wf[1][1][l] +                    \
              V1.z * wf[1][2][l] + V1.w * wf[1][3][l] +                    \
              V2.x * wf[2][0][l] + V2.y * wf[2][1][l] +                    \
              V2.z * wf[2][2][l] + V2.w * wf[2][3][l];                     \
      dd[l] = wave_sum63(dd[l]);                                           \
    }                                                                      \
    if (lane == 63) {                                                      \
      float* dst = proj + (size_t)(t0 + (K)) * PSTRIDE;                    \
      *(float4*)(dst) = make_float4(dd[0], dd[1], dd[2], dd[3]);           \
      *(float4*)(dst + 4) = make_float4(dd[4], dd[5], dd[6], dd[7]);       \
      dst[8] = dd[8];                                                      \
    }                                                                      \
  }

  LDT(A0, A1, A2, 0)
  int k = 0;
  while (true) {
    if (k + 1 < vc) LDT(B0, B1, B2, k + 1)
    PRT(A0, A1, A2, k)
    if (++k >= vc) break;
    if (k + 1 < vc) LDT(A0, A1, A2, k + 1)
    PRT(B0, B1, B2, k)
    if (++k >= vc) break;
  }
#undef LDT
#undef PRT
}

// ---------------------------------------------------------------------------
// Kernel 2 (R9 rowword, proven): one block per batch row (512 threads).
//  A: both scans in LDS (p2t, wstart, nvalid); B: 400 words: mean of token
//  proj rows (L2-resident), +bias, argmax -> out, NLL partial; C: block
//  reduce, 64 block atomics, last block finalizes loss.
// ---------------------------------------------------------------------------
__global__ __launch_bounds__(Tdim) void rowword_kernel(
    const float* __restrict__ proj, const float* __restrict__ bias,
    const int* __restrict__ attn, const int* __restrict__ ids_lens,
    const int* __restrict__ label_ids, float* __restrict__ out,
    float* __restrict__ accum, unsigned* __restrict__ counter) {
  int b = blockIdx.x;
  int tid = threadIdx.x;
  int lane = tid & 63, wid = tid >> 6;
  __shared__ int p2t[Tdim];
  __shared__ int wst[Sdim];
  __shared__ int wsum[8];
  __shared__ int totsm;
  __shared__ float ssm[8], csm[8];

  // ---- scan 1: attention mask -> p2t (LDS), nvalid ----
  int m = attn[b * Tdim + tid];
  int x = m;
#pragma unroll
  for (int off = 1; off < 64; off <<= 1) {
    int v = __shfl_up(x, off, 64);
    if (lane >= off) x += v;
  }
  if (lane == 63) wsum[wid] = x;
  __syncthreads();
  if (tid < 8) {
    int s = wsum[tid], y = s;
#pragma unroll
    for (int off = 1; off < 8; off <<= 1) {
      int v = __shfl_up(y, off, 64);
      if (tid >= off) y += v;
    }
    wsum[tid] = y - s;
    if (tid == 7) totsm = y;
  }
  __syncthreads();
  x += wsum[wid];
  if (m) p2t[x - 1] = tid;  // q-th valid token -> physical position
  int nv_local = totsm;
  __syncthreads();

  // ---- scan 2: ids_lens -> wstart (LDS) ----
  int len = (tid < Sdim) ? ids_lens[b * Sdim + tid] : 0;
  int x2 = len;
#pragma unroll
  for (int off = 1; off < 64; off <<= 1) {
    int v = __shfl_up(x2, off, 64);
    if (lane >= off) x2 += v;
  }
  if (lane == 63) wsum[wid] = x2;
  __syncthreads();
  if (tid < 8) {
    int s = wsum[tid], y = s;
#pragma unroll
    for (int off = 1; off < 8; off <<= 1) {
      int v = __shfl_up(y, off, 64);
      if (tid >= off) y += v;
    }
    wsum[tid] = y - s;
  }
  __syncthreads();
  x2 += wsum[wid];
  if (tid < Sdim) wst[tid] = x2 - len;
  __syncthreads();

  // ---- phase B: words ----
  float nll = 0.0f, cnt = 0.0f;
  if (tid < Sdim) {
    int bs = b * Sdim + tid;
    float sum[Ldim];
#pragma unroll
    for (int l = 0; l < Ldim; ++l) sum[l] = 0.0f;
    if (len > 0) {
      int start = wst[tid];
      for (int j = 0; j < len; ++j) {
        int q = start + j;
        if (q >= nv_local) break;
        const float* pr = proj + ((size_t)(b << 9) + p2t[q]) * PSTRIDE;
        const float4* pr4 = (const float4*)pr;
        float4 r0 = pr4[0], r1 = pr4[1];
        float r8 = pr[8];
        sum[0] += r0.x; sum[1] += r0.y; sum[2] += r0.z; sum[3] += r0.w;
        sum[4] += r1.x; sum[5] += r1.y; sum[6] += r1.z; sum[7] += r1.w;
        sum[8] += r8;
      }
    }
    float inv = (len > 0) ? 1.0f / (float)len : 0.0f;
    float lg[Ldim];
#pragma unroll
    for (int l = 0; l < Ldim; ++l) lg[l] = sum[l] * inv + bias[l];

    int amax = 0;
    float mx = lg[0];
#pragma unroll
    for (int l = 1; l < Ldim; ++l)
      if (lg[l] > mx) { mx = lg[l]; amax = l; }
    out[1 + bs] = (float)amax;

    if (len > 0) {
      float se = 0.0f;
#pragma unroll
      for (int l = 0; l < Ldim; ++l) se += expf(lg[l] - mx);
      float lse = mx + logf(se);
      int lab = label_ids[bs];
      float ll = lg[0];
#pragma unroll
      for (int l = 1; l < Ldim; ++l) ll = (lab == l) ? lg[l] : ll;
      nll = lse - ll;
      cnt = 1.0f;
    }
  }

  // ---- phase C: block reduce + finalize ----
#pragma unroll
  for (int off = 32; off > 0; off >>= 1) {
    nll += __shfl_down(nll, off, 64);
    cnt += __shfl_down(cnt, off, 64);
  }
  if (lane == 0) { ssm[wid] = nll; csm[wid] = cnt; }
  __syncthreads();
  if (tid == 0) {
    float S = 0.f, C = 0.f;
#pragma unroll
    for (int k = 0; k < 8; ++k) { S += ssm[k]; C += csm[k]; }
    atomicAdd(&accum[0], S);
    atomicAdd(&accum[1], C);
    __threadfence();
    unsigned prev = atomicAdd(counter, 1u);
    if (prev == gridDim.x - 1) {
      __threadfence();
      float Sf = atomicAdd(&accum[0], 0.0f);
      float Cf = atomicAdd(&accum[1], 0.0f);
      out[0] = Sf / Cf;
    }
  }
}

extern "C" void kernel_launch(void* const* d_in, const int* in_sizes, int n_in,
                              void* d_out, int out_size, void* d_ws, size_t ws_size,
                              hipStream_t stream) {
  const float* enc     = (const float*)d_in[0];  // [B,T,H] f32
  const float* W       = (const float*)d_in[1];  // [H,L]   f32
  const float* bias    = (const float*)d_in[2];  // [L]     f32
  const int* attn      = (const int*)d_in[3];    // [B,T]   i32
  const int* ids_lens  = (const int*)d_in[4];    // [B,S]   i32
  const int* label_ids = (const int*)d_in[5];    // [B,S]   i32
  // d_in[6] label_mask is recomputed from ids_lens>0

  float* out = (float*)d_out;  // [1 + B*S]: loss, then argmax as float

  char* ws = (char*)d_ws;
  size_t off0 = 0;
  float* accum      = (float*)(ws + off0);    off0 += 128;
  unsigned* counter = (unsigned*)(ws + off0); off0 += 128;
  float* proj       = (float*)(ws + off0);    off0 += (size_t)Bdim * Tdim * PSTRIDE * sizeof(float);

  int nwaves = (Bdim * Tdim) / TPW;          // 1024
  proj_kernel<<<nwaves / 4, 256, 0, stream>>>(enc, W, attn, proj, accum, counter);
  rowword_kernel<<<Bdim, Tdim, 0, stream>>>(proj, bias, attn, ids_lens,
                                            label_ids, out, accum, counter);
}